// Round 1
// baseline (1168.015 us; speedup 1.0000x reference)
//
#include <hip/hip_runtime.h>

#define DD 64   // feature dim
#define GG 64   // graphs per batch

// ---------------- degree / norm ----------------
__global__ __launch_bounds__(256) void k_count_deg(const int* __restrict__ dst, int E,
                                                   int* __restrict__ degI) {
    int i = blockIdx.x * 256 + threadIdx.x;
    if (i < E) atomicAdd(&degI[dst[i]], 1);
}

// in-place: degI (int counts, excl. self-loop) -> dis = rsqrt(deg+1) as float
__global__ __launch_bounds__(256) void k_dis(int N, float* __restrict__ disv) {
    int i = blockIdx.x * 256 + threadIdx.x;
    if (i < N) {
        int d = ((const int*)disv)[i];
        disv[i] = rsqrtf((float)(d + 1));
    }
}

// ---------------- nodes-per-graph counts ----------------
__global__ __launch_bounds__(256) void k_count_batch(const int* __restrict__ batch, int N,
                                                     int* __restrict__ cntI) {
    __shared__ int h[GG];
    if (threadIdx.x < GG) h[threadIdx.x] = 0;
    __syncthreads();
    int i = blockIdx.x * 256 + threadIdx.x;
    if (i < N) atomicAdd(&h[batch[i]], 1);
    __syncthreads();
    if (threadIdx.x < GG) {
        int v = h[threadIdx.x];
        if (v) atomicAdd(&cntI[threadIdx.x], v);
    }
}

// ---------------- g = (x @ W) * dis[row] ----------------
__global__ __launch_bounds__(256) void k_gemm(const float* __restrict__ x,
                                              const float* __restrict__ W,
                                              const float* __restrict__ disv,
                                              float* __restrict__ g, int N) {
    __shared__ float Ws[DD * DD];
    for (int t = threadIdx.x; t < DD * DD; t += 256) Ws[t] = W[t];
    __syncthreads();
    int lane = threadIdx.x & 63;
    int wave = (blockIdx.x * 256 + threadIdx.x) >> 6;
    int nw   = (gridDim.x * 256) >> 6;
    for (int r = wave; r < N; r += nw) {
        float xv  = x[(size_t)r * DD + lane];
        float acc = 0.f;
#pragma unroll
        for (int k = 0; k < DD; ++k)
            acc += __shfl(xv, k) * Ws[k * DD + lane];
        g[(size_t)r * DD + lane] = acc * disv[r];
    }
}

// ---------------- edge scatter: agg[dst] += g[src] ----------------
__global__ __launch_bounds__(256) void k_scatter(const int* __restrict__ src,
                                                 const int* __restrict__ dst, int E,
                                                 const float* __restrict__ g,
                                                 float* __restrict__ agg) {
    int lane = threadIdx.x & 63;
    int wave = (blockIdx.x * 256 + threadIdx.x) >> 6;
    int nw   = (gridDim.x * 256) >> 6;
    for (int e = wave; e < E; e += nw) {
        int s = src[e], d = dst[e];
        float v = g[(size_t)s * DD + lane];
        atomicAdd(&agg[(size_t)d * DD + lane], v);
    }
}

// ---------------- finalize: x = relu(dis*(agg + g) + b), fused pooling ----------------
// gacc layout: [GG][2*DD]: cols 0..63 = running max (f32 bits, monotone for >=0),
//                          cols 64..127 = running sum
__global__ __launch_bounds__(256) void k_finalize(const float* __restrict__ g,
                                                  const float* __restrict__ agg,
                                                  const float* __restrict__ disv,
                                                  const float* __restrict__ b,
                                                  const int* __restrict__ batch,
                                                  float* __restrict__ xout,
                                                  float* __restrict__ gacc, int N) {
    int lane = threadIdx.x & 63;
    int w    = threadIdx.x >> 6;
    int base = blockIdx.x * 64 + w * 16;   // 16 contiguous nodes per wave
    if (base >= N) return;
    int end = min(base + 16, N);
    float bj = b[lane];
    float vmax = 0.f, vsum = 0.f;
    int curg = batch[base];
    for (int i = base; i < end; ++i) {
        int gid = batch[i];
        if (gid != curg) {
            atomicMax((unsigned*)&gacc[curg * 2 * DD + lane], __float_as_uint(vmax));
            atomicAdd(&gacc[curg * 2 * DD + DD + lane], vsum);
            vmax = 0.f; vsum = 0.f; curg = gid;
        }
        float v = disv[i] * (agg[(size_t)i * DD + lane] + g[(size_t)i * DD + lane]) + bj;
        v = fmaxf(v, 0.f);
        xout[(size_t)i * DD + lane] = v;
        vmax = fmaxf(vmax, v);
        vsum += v;
    }
    atomicMax((unsigned*)&gacc[curg * 2 * DD + lane], __float_as_uint(vmax));
    atomicAdd(&gacc[curg * 2 * DD + DD + lane], vsum);
}

// ---------------- fold per-layer pool into running total; clear gacc ----------------
__global__ __launch_bounds__(256) void k_pool(float* __restrict__ gacc,
                                              float* __restrict__ gtot,
                                              const int* __restrict__ cntI) {
    int i = blockIdx.x * 256 + threadIdx.x;
    if (i < GG * 2 * DD) {
        int gidx = i >> 7;       // / (2*DD)
        int j    = i & 127;
        float v  = gacc[i];      // max part: stored bits == float value (>=0)
        if (j >= DD) v = v / (float)cntI[gidx];
        gtot[i] += v;
        gacc[i] = 0.f;
    }
}

__global__ __launch_bounds__(256) void k_copy(const float* __restrict__ srcp,
                                              float* __restrict__ dstp, int n) {
    int i = blockIdx.x * 256 + threadIdx.x;
    if (i < n) dstp[i] = srcp[i];
}

extern "C" void kernel_launch(void* const* d_in, const int* in_sizes, int n_in,
                              void* d_out, int out_size, void* d_ws, size_t ws_size,
                              hipStream_t stream) {
    const float* x     = (const float*)d_in[0];
    const int*   ei    = (const int*)d_in[1];
    const int*   batch = (const int*)d_in[2];

    int N = in_sizes[0] / DD;
    int E = in_sizes[1] / 2;
    const int* src = ei;
    const int* dst = ei + E;

    size_t nd = (size_t)N * DD;
    float* ws   = (float*)d_ws;
    float* bufX = ws;                 // intermediate node features
    float* bufG = ws + nd;            // g = (xW)*dis
    float* bufA = ws + 2 * nd;        // edge-sum accumulator
    float* disv = ws + 3 * nd;        // N floats (ints during counting)
    float* gacc = disv + N;           // GG*2*DD per-layer pool scratch
    float* gtot = gacc + GG * 2 * DD; // GG*2*DD running total
    int*   cntI = (int*)(gtot + GG * 2 * DD);

    hipMemsetAsync(disv, 0, (size_t)N * sizeof(int), stream);
    hipMemsetAsync(gacc, 0, (size_t)GG * 2 * DD * sizeof(float), stream);
    hipMemsetAsync(gtot, 0, (size_t)GG * 2 * DD * sizeof(float), stream);
    hipMemsetAsync(cntI, 0, (size_t)GG * sizeof(int), stream);

    k_count_deg<<<(E + 255) / 256, 256, 0, stream>>>(dst, E, (int*)disv);
    k_dis<<<(N + 255) / 256, 256, 0, stream>>>(N, disv);
    k_count_batch<<<(N + 255) / 256, 256, 0, stream>>>(batch, N, cntI);

    const float* xin = x;
    for (int l = 0; l < 3; ++l) {
        const float* W = (const float*)d_in[3 + 2 * l];
        const float* b = (const float*)d_in[4 + 2 * l];
        hipMemsetAsync(bufA, 0, nd * sizeof(float), stream);
        k_gemm<<<1024, 256, 0, stream>>>(xin, W, disv, bufG, N);
        k_scatter<<<2048, 256, 0, stream>>>(src, dst, E, bufG, bufA);
        float* xout = (l == 2) ? (float*)d_out : bufX;
        k_finalize<<<(N + 63) / 64, 256, 0, stream>>>(bufG, bufA, disv, b, batch, xout,
                                                      gacc, N);
        k_pool<<<(GG * 2 * DD + 255) / 256, 256, 0, stream>>>(gacc, gtot, cntI);
        xin = bufX;
    }
    k_copy<<<(GG * 2 * DD + 255) / 256, 256, 0, stream>>>(gtot, (float*)d_out + nd,
                                                          GG * 2 * DD);
}

// Round 2
// 580.956 us; speedup vs baseline: 2.0105x; 2.0105x over previous
//
#include <hip/hip_runtime.h>

#define DD 64   // feature dim
#define GG 64   // graphs per batch

// ---------------- degree count (in-edges, excl self-loop) ----------------
__global__ __launch_bounds__(256) void k_count_deg(const int* __restrict__ dst, int E,
                                                   int* __restrict__ degI) {
    int i = blockIdx.x * 256 + threadIdx.x;
    if (i < E) atomicAdd(&degI[dst[i]], 1);
}

// dis = rsqrt(deg + 1)  (self-loop included in normalization)
__global__ __launch_bounds__(256) void k_dis(const int* __restrict__ degI, int N,
                                             float* __restrict__ disv) {
    int i = blockIdx.x * 256 + threadIdx.x;
    if (i < N) disv[i] = rsqrtf((float)(degI[i] + 1));
}

// ---------------- nodes-per-graph counts ----------------
__global__ __launch_bounds__(256) void k_count_batch(const int* __restrict__ batch, int N,
                                                     int* __restrict__ cntI) {
    __shared__ int h[GG];
    if (threadIdx.x < GG) h[threadIdx.x] = 0;
    __syncthreads();
    int i = blockIdx.x * 256 + threadIdx.x;
    if (i < N) atomicAdd(&h[batch[i]], 1);
    __syncthreads();
    if (threadIdx.x < GG) {
        int v = h[threadIdx.x];
        if (v) atomicAdd(&cntI[threadIdx.x], v);
    }
}

// ---------------- exclusive scan of degI -> offs (3-pass) ----------------
__global__ __launch_bounds__(256) void k_scan1(const int* __restrict__ degI, int N,
                                               int* __restrict__ offs,
                                               int* __restrict__ bsum) {
    __shared__ int sh[256];
    int t = threadIdx.x;
    int base = blockIdx.x * 1024 + t * 4;
    int v0 = (base + 0 < N) ? degI[base + 0] : 0;
    int v1 = (base + 1 < N) ? degI[base + 1] : 0;
    int v2 = (base + 2 < N) ? degI[base + 2] : 0;
    int v3 = (base + 3 < N) ? degI[base + 3] : 0;
    int s = v0 + v1 + v2 + v3;
    sh[t] = s;
    __syncthreads();
    for (int off = 1; off < 256; off <<= 1) {
        int x = (t >= off) ? sh[t - off] : 0;
        __syncthreads();
        sh[t] += x;
        __syncthreads();
    }
    int excl = sh[t] - s;
    if (t == 255) bsum[blockIdx.x] = sh[255];
    if (base + 0 < N) offs[base + 0] = excl;
    excl += v0;
    if (base + 1 < N) offs[base + 1] = excl;
    excl += v1;
    if (base + 2 < N) offs[base + 2] = excl;
    excl += v2;
    if (base + 3 < N) offs[base + 3] = excl;
}

__global__ void k_scan2(int* __restrict__ bsum, int nb) {
    if (threadIdx.x == 0 && blockIdx.x == 0) {
        int run = 0;
        for (int j = 0; j < nb; ++j) {
            int t = bsum[j];
            bsum[j] = run;
            run += t;
        }
    }
}

__global__ __launch_bounds__(256) void k_scan3(int* __restrict__ offs,
                                               const int* __restrict__ bsum, int N) {
    int i = blockIdx.x * 256 + threadIdx.x;
    if (i < N) offs[i] += bsum[i >> 10];
}

// ---------------- CSR fill: csr[offs[d] + slot] = src ----------------
__global__ __launch_bounds__(256) void k_fill(const int* __restrict__ src,
                                              const int* __restrict__ dst, int E,
                                              const int* __restrict__ offs,
                                              int* __restrict__ cursor,
                                              int* __restrict__ csr) {
    int i = blockIdx.x * 256 + threadIdx.x;
    if (i < E) {
        int d = dst[i];
        int p = atomicAdd(&cursor[d], 1);
        csr[offs[d] + p] = src[i];
    }
}

// ---------------- g = (x @ W) * dis[row] ----------------
__global__ __launch_bounds__(256) void k_gemm(const float* __restrict__ x,
                                              const float* __restrict__ W,
                                              const float* __restrict__ disv,
                                              float* __restrict__ g, int N) {
    __shared__ float Ws[DD * DD];
    for (int t = threadIdx.x; t < DD * DD; t += 256) Ws[t] = W[t];
    __syncthreads();
    int lane = threadIdx.x & 63;
    int wave = (blockIdx.x * 256 + threadIdx.x) >> 6;
    int nw   = (gridDim.x * 256) >> 6;
    for (int r = wave; r < N; r += nw) {
        float xv  = x[(size_t)r * DD + lane];
        float acc = 0.f;
#pragma unroll
        for (int k = 0; k < DD; ++k)
            acc += __shfl(xv, k) * Ws[k * DD + lane];
        g[(size_t)r * DD + lane] = acc * disv[r];
    }
}

// ---------------- fused aggregate + finalize + pooling ----------------
// per node: v = relu(dis[i]*(sum_{in-edges} g[src] + g[i]) + b); xout[i]=v
// pooling: run-accumulate over sorted batch, flush via atomics into gacc
__global__ __launch_bounds__(256) void k_agg(const int* __restrict__ csr,
                                             const int* __restrict__ offs,
                                             const int* __restrict__ degI,
                                             const float* __restrict__ g,
                                             const float* __restrict__ disv,
                                             const float* __restrict__ b,
                                             const int* __restrict__ batch,
                                             float* __restrict__ xout,
                                             float* __restrict__ gacc, int N) {
    int lane = threadIdx.x & 63;
    int wave = (blockIdx.x * 256 + threadIdx.x) >> 6;
    int nw   = (gridDim.x * 256) >> 6;
    float bj = b[lane];
    int nchunks = (N + 15) >> 4;
    for (int c = wave; c < nchunks; c += nw) {
        int base = c * 16;
        int end  = min(base + 16, N);
        float vmax = 0.f, vsum = 0.f;
        int curg = batch[base];
        for (int i = base; i < end; ++i) {
            int start = offs[i];
            int cnt   = degI[i];
            float sum = g[(size_t)i * DD + lane];   // self-loop message
            int k = 0;
            while (k < cnt) {
                int kk = min(cnt - k, 64);
                int eidx = (lane < kk) ? csr[start + k + lane] : 0;
                int j = 0;
                for (; j + 3 < kk; j += 4) {
                    int s0 = __shfl(eidx, j + 0);
                    int s1 = __shfl(eidx, j + 1);
                    int s2 = __shfl(eidx, j + 2);
                    int s3 = __shfl(eidx, j + 3);
                    float v0 = g[(size_t)s0 * DD + lane];
                    float v1 = g[(size_t)s1 * DD + lane];
                    float v2 = g[(size_t)s2 * DD + lane];
                    float v3 = g[(size_t)s3 * DD + lane];
                    sum += v0; sum += v1; sum += v2; sum += v3;
                }
                for (; j < kk; ++j) {
                    int s = __shfl(eidx, j);
                    sum += g[(size_t)s * DD + lane];
                }
                k += kk;
            }
            float v = disv[i] * sum + bj;
            v = fmaxf(v, 0.f);
            xout[(size_t)i * DD + lane] = v;
            int gid = batch[i];
            if (gid != curg) {
                atomicMax((unsigned*)&gacc[curg * 2 * DD + lane], __float_as_uint(vmax));
                atomicAdd(&gacc[curg * 2 * DD + DD + lane], vsum);
                vmax = 0.f; vsum = 0.f; curg = gid;
            }
            vmax = fmaxf(vmax, v);
            vsum += v;
        }
        atomicMax((unsigned*)&gacc[curg * 2 * DD + lane], __float_as_uint(vmax));
        atomicAdd(&gacc[curg * 2 * DD + DD + lane], vsum);
    }
}

// ---------------- fold per-layer pool into running total; clear gacc ----------------
__global__ __launch_bounds__(256) void k_pool(float* __restrict__ gacc,
                                              float* __restrict__ gtot,
                                              const int* __restrict__ cntI) {
    int i = blockIdx.x * 256 + threadIdx.x;
    if (i < GG * 2 * DD) {
        int gidx = i >> 7;
        int j    = i & 127;
        float v  = gacc[i];
        if (j >= DD) v = v / (float)cntI[gidx];
        gtot[i] += v;
        gacc[i] = 0.f;
    }
}

__global__ __launch_bounds__(256) void k_copy(const float* __restrict__ srcp,
                                              float* __restrict__ dstp, int n) {
    int i = blockIdx.x * 256 + threadIdx.x;
    if (i < n) dstp[i] = srcp[i];
}

extern "C" void kernel_launch(void* const* d_in, const int* in_sizes, int n_in,
                              void* d_out, int out_size, void* d_ws, size_t ws_size,
                              hipStream_t stream) {
    const float* x     = (const float*)d_in[0];
    const int*   ei    = (const int*)d_in[1];
    const int*   batch = (const int*)d_in[2];

    int N = in_sizes[0] / DD;
    int E = in_sizes[1] / 2;
    const int* src = ei;
    const int* dst = ei + E;

    size_t nd = (size_t)N * DD;
    float* ws     = (float*)d_ws;
    float* bufX   = ws;                     // intermediate node features
    float* bufG   = ws + nd;                // g = (xW)*dis
    float* disv   = ws + 2 * nd;            // N floats
    float* gacc   = disv + N;               // GG*2*DD per-layer pool scratch
    float* gtot   = gacc + GG * 2 * DD;     // GG*2*DD running total
    int*   cntI   = (int*)(gtot + GG * 2 * DD);   // GG
    int*   degI   = cntI + GG;              // N
    int*   offs   = degI + N;               // N
    int*   cursor = offs + N;               // N
    int*   bsum   = cursor + N;             // 128
    int*   csr    = bsum + 128;             // E

    hipMemsetAsync(degI, 0, (size_t)N * sizeof(int), stream);
    hipMemsetAsync(cursor, 0, (size_t)N * sizeof(int), stream);
    hipMemsetAsync(gacc, 0, (size_t)GG * 2 * DD * sizeof(float), stream);
    hipMemsetAsync(gtot, 0, (size_t)GG * 2 * DD * sizeof(float), stream);
    hipMemsetAsync(cntI, 0, (size_t)GG * sizeof(int), stream);

    k_count_deg<<<(E + 255) / 256, 256, 0, stream>>>(dst, E, degI);
    k_dis<<<(N + 255) / 256, 256, 0, stream>>>(degI, N, disv);
    k_count_batch<<<(N + 255) / 256, 256, 0, stream>>>(batch, N, cntI);

    int nb = (N + 1023) / 1024;
    k_scan1<<<nb, 256, 0, stream>>>(degI, N, offs, bsum);
    k_scan2<<<1, 64, 0, stream>>>(bsum, nb);
    k_scan3<<<(N + 255) / 256, 256, 0, stream>>>(offs, bsum, N);
    k_fill<<<(E + 255) / 256, 256, 0, stream>>>(src, dst, E, offs, cursor, csr);

    const float* xin = x;
    for (int l = 0; l < 3; ++l) {
        const float* W = (const float*)d_in[3 + 2 * l];
        const float* b = (const float*)d_in[4 + 2 * l];
        k_gemm<<<1024, 256, 0, stream>>>(xin, W, disv, bufG, N);
        float* xout = (l == 2) ? (float*)d_out : bufX;
        k_agg<<<1600, 256, 0, stream>>>(csr, offs, degI, bufG, disv, b, batch, xout,
                                        gacc, N);
        k_pool<<<(GG * 2 * DD + 255) / 256, 256, 0, stream>>>(gacc, gtot, cntI);
        xin = bufX;
    }
    k_copy<<<(GG * 2 * DD + 255) / 256, 256, 0, stream>>>(gtot, (float*)d_out + nd,
                                                          GG * 2 * DD);
}

// Round 3
// 535.395 us; speedup vs baseline: 2.1816x; 1.0851x over previous
//
#include <hip/hip_runtime.h>
#include <hip/hip_fp16.h>

#define DD 64   // feature dim
#define GG 64   // graphs per batch
#define CHUNK 16  // nodes per bucket (one wave per bucket)

// ---------------- degree count (in-edges, excl self-loop) ----------------
__global__ __launch_bounds__(256) void k_count_deg(const int* __restrict__ dst, int E,
                                                   int* __restrict__ degI) {
    int i = blockIdx.x * 256 + threadIdx.x;
    if (i < E) atomicAdd(&degI[dst[i]], 1);
}

// dis = rsqrt(deg + 1)  (self-loop included in normalization)
__global__ __launch_bounds__(256) void k_dis(const int* __restrict__ degI, int N,
                                             float* __restrict__ disv) {
    int i = blockIdx.x * 256 + threadIdx.x;
    if (i < N) disv[i] = rsqrtf((float)(degI[i] + 1));
}

// ---------------- nodes-per-graph counts ----------------
__global__ __launch_bounds__(256) void k_count_batch(const int* __restrict__ batch, int N,
                                                     int* __restrict__ cntI) {
    __shared__ int h[GG];
    if (threadIdx.x < GG) h[threadIdx.x] = 0;
    __syncthreads();
    int i = blockIdx.x * 256 + threadIdx.x;
    if (i < N) atomicAdd(&h[batch[i]], 1);
    __syncthreads();
    if (threadIdx.x < GG) {
        int v = h[threadIdx.x];
        if (v) atomicAdd(&cntI[threadIdx.x], v);
    }
}

// ---------------- exclusive scan of degI -> offs (3-pass) ----------------
__global__ __launch_bounds__(256) void k_scan1(const int* __restrict__ degI, int N,
                                               int* __restrict__ offs,
                                               int* __restrict__ bsum) {
    __shared__ int sh[256];
    int t = threadIdx.x;
    int base = blockIdx.x * 1024 + t * 4;
    int v0 = (base + 0 < N) ? degI[base + 0] : 0;
    int v1 = (base + 1 < N) ? degI[base + 1] : 0;
    int v2 = (base + 2 < N) ? degI[base + 2] : 0;
    int v3 = (base + 3 < N) ? degI[base + 3] : 0;
    int s = v0 + v1 + v2 + v3;
    sh[t] = s;
    __syncthreads();
    for (int off = 1; off < 256; off <<= 1) {
        int x = (t >= off) ? sh[t - off] : 0;
        __syncthreads();
        sh[t] += x;
        __syncthreads();
    }
    int excl = sh[t] - s;
    if (t == 255) bsum[blockIdx.x] = sh[255];
    if (base + 0 < N) offs[base + 0] = excl;
    excl += v0;
    if (base + 1 < N) offs[base + 1] = excl;
    excl += v1;
    if (base + 2 < N) offs[base + 2] = excl;
    excl += v2;
    if (base + 3 < N) offs[base + 3] = excl;
}

__global__ void k_scan2(int* __restrict__ bsum, int nb) {
    if (threadIdx.x == 0 && blockIdx.x == 0) {
        int run = 0;
        for (int j = 0; j < nb; ++j) {
            int t = bsum[j];
            bsum[j] = run;
            run += t;
        }
    }
}

__global__ __launch_bounds__(256) void k_scan3(int* __restrict__ offs,
                                               const int* __restrict__ bsum, int N) {
    int i = blockIdx.x * 256 + threadIdx.x;
    if (i < N) offs[i] += bsum[i >> 10];
}

// ---------------- bucketed partition: pairs[boffs[b] + slot] = src | local<<20 ----
// bucket b covers dst nodes [16b, 16b+16); boffs[b] = offs[16b] (free from scan)
__global__ __launch_bounds__(256) void k_part(const int* __restrict__ src,
                                              const int* __restrict__ dst, int E,
                                              const int* __restrict__ offs,
                                              int* __restrict__ bcur,
                                              unsigned* __restrict__ pairs) {
    int i = blockIdx.x * 256 + threadIdx.x;
    if (i < E) {
        int d  = dst[i];
        int bu = d >> 4;
        int p  = atomicAdd(&bcur[bu], 1);
        pairs[offs[bu << 4] + p] = (unsigned)src[i] | ((unsigned)(d & 15) << 20);
    }
}

// ---------------- g = fp16((x @ W) * dis[row]) ----------------
__global__ __launch_bounds__(256) void k_gemm(const float* __restrict__ x,
                                              const float* __restrict__ W,
                                              const float* __restrict__ disv,
                                              __half* __restrict__ g, int N) {
    __shared__ float Ws[DD * DD];
    for (int t = threadIdx.x; t < DD * DD; t += 256) Ws[t] = W[t];
    __syncthreads();
    int lane = threadIdx.x & 63;
    int wave = (blockIdx.x * 256 + threadIdx.x) >> 6;
    int nw   = (gridDim.x * 256) >> 6;
    for (int r = wave; r < N; r += nw) {
        float xv  = x[(size_t)r * DD + lane];
        float acc = 0.f;
#pragma unroll
        for (int k = 0; k < DD; ++k)
            acc += __shfl(xv, k) * Ws[k * DD + lane];
        g[(size_t)r * DD + lane] = __float2half(acc * disv[r]);
    }
}

// ---------------- fused aggregate + finalize + pooling (one wave per bucket) ----
__global__ __launch_bounds__(256) void k_agg(const unsigned* __restrict__ pairs,
                                             const int* __restrict__ offs,
                                             const __half* __restrict__ g,
                                             const float* __restrict__ disv,
                                             const float* __restrict__ b,
                                             const int* __restrict__ batch,
                                             float* __restrict__ xout,
                                             float* __restrict__ gacc, int N, int E) {
    __shared__ float acc_s[4][CHUNK * DD];   // 16 KB/block, wave-private slices
    int lane = threadIdx.x & 63;
    int w    = threadIdx.x >> 6;
    float* acc = acc_s[w];
    int wave = (blockIdx.x * 256 + threadIdx.x) >> 6;
    int nw   = (gridDim.x * 256) >> 6;
    int NB   = (N + CHUNK - 1) / CHUNK;
    float bj = b[lane];
    for (int bu = wave; bu < NB; bu += nw) {
        int nbase  = bu * CHUNK;
        int nend   = min(nbase + CHUNK, N);
        int bstart = offs[nbase];
        int bend   = (nbase + CHUNK >= N) ? E : offs[nbase + CHUNK];
#pragma unroll
        for (int t = 0; t < CHUNK; ++t) acc[t * DD + lane] = 0.f;
        for (int k = bstart; k < bend; k += 64) {
            int kk = min(bend - k, 64);
            unsigned pk = (lane < kk) ? pairs[k + lane] : 0u;
            int j = 0;
            for (; j + 3 < kk; j += 4) {
                unsigned p0 = __shfl(pk, j + 0);
                unsigned p1 = __shfl(pk, j + 1);
                unsigned p2 = __shfl(pk, j + 2);
                unsigned p3 = __shfl(pk, j + 3);
                float v0 = __half2float(g[(size_t)(p0 & 0xFFFFFu) * DD + lane]);
                float v1 = __half2float(g[(size_t)(p1 & 0xFFFFFu) * DD + lane]);
                float v2 = __half2float(g[(size_t)(p2 & 0xFFFFFu) * DD + lane]);
                float v3 = __half2float(g[(size_t)(p3 & 0xFFFFFu) * DD + lane]);
                acc[(p0 >> 20) * DD + lane] += v0;
                acc[(p1 >> 20) * DD + lane] += v1;
                acc[(p2 >> 20) * DD + lane] += v2;
                acc[(p3 >> 20) * DD + lane] += v3;
            }
            for (; j < kk; ++j) {
                unsigned p = __shfl(pk, j);
                acc[(p >> 20) * DD + lane] +=
                    __half2float(g[(size_t)(p & 0xFFFFFu) * DD + lane]);
            }
        }
        // finalize 16 nodes + fused pooling (batch is sorted)
        float vmax = 0.f, vsum = 0.f;
        int curg = batch[nbase];
        for (int i = nbase; i < nend; ++i) {
            float self = __half2float(g[(size_t)i * DD + lane]);
            float v = disv[i] * (acc[(i - nbase) * DD + lane] + self) + bj;
            v = fmaxf(v, 0.f);
            xout[(size_t)i * DD + lane] = v;
            int gid = batch[i];
            if (gid != curg) {
                atomicMax((unsigned*)&gacc[curg * 2 * DD + lane], __float_as_uint(vmax));
                atomicAdd(&gacc[curg * 2 * DD + DD + lane], vsum);
                vmax = 0.f; vsum = 0.f; curg = gid;
            }
            vmax = fmaxf(vmax, v);
            vsum += v;
        }
        atomicMax((unsigned*)&gacc[curg * 2 * DD + lane], __float_as_uint(vmax));
        atomicAdd(&gacc[curg * 2 * DD + DD + lane], vsum);
    }
}

// ---------------- fold per-layer pool into running total; clear gacc ----------------
__global__ __launch_bounds__(256) void k_pool(float* __restrict__ gacc,
                                              float* __restrict__ gtot,
                                              const int* __restrict__ cntI) {
    int i = blockIdx.x * 256 + threadIdx.x;
    if (i < GG * 2 * DD) {
        int gidx = i >> 7;
        int j    = i & 127;
        float v  = gacc[i];
        if (j >= DD) v = v / (float)cntI[gidx];
        gtot[i] += v;
        gacc[i] = 0.f;
    }
}

__global__ __launch_bounds__(256) void k_copy(const float* __restrict__ srcp,
                                              float* __restrict__ dstp, int n) {
    int i = blockIdx.x * 256 + threadIdx.x;
    if (i < n) dstp[i] = srcp[i];
}

extern "C" void kernel_launch(void* const* d_in, const int* in_sizes, int n_in,
                              void* d_out, int out_size, void* d_ws, size_t ws_size,
                              hipStream_t stream) {
    const float* x     = (const float*)d_in[0];
    const int*   ei    = (const int*)d_in[1];
    const int*   batch = (const int*)d_in[2];

    int N = in_sizes[0] / DD;
    int E = in_sizes[1] / 2;
    const int* src = ei;
    const int* dst = ei + E;

    size_t nd = (size_t)N * DD;
    int NB = (N + CHUNK - 1) / CHUNK;

    float*    ws    = (float*)d_ws;
    float*    bufX  = ws;                       // N*DD f32 intermediate features
    __half*   bufG  = (__half*)(ws + nd);       // N*DD fp16 messages (g)
    float*    disv  = ws + nd + nd / 2;         // N f32
    float*    gacc  = disv + N;                 // GG*2*DD
    float*    gtot  = gacc + GG * 2 * DD;       // GG*2*DD
    int*      cntI  = (int*)(gtot + GG * 2 * DD);  // GG
    int*      degI  = cntI + GG;                // N
    int*      offs  = degI + N;                 // N
    int*      bcur  = offs + N;                 // NB
    int*      bsum  = bcur + NB;                // 128
    unsigned* pairs = (unsigned*)(bsum + 128);  // E

    hipMemsetAsync(degI, 0, (size_t)N * sizeof(int), stream);
    hipMemsetAsync(bcur, 0, (size_t)NB * sizeof(int), stream);
    hipMemsetAsync(gacc, 0, (size_t)GG * 2 * DD * sizeof(float), stream);
    hipMemsetAsync(gtot, 0, (size_t)GG * 2 * DD * sizeof(float), stream);
    hipMemsetAsync(cntI, 0, (size_t)GG * sizeof(int), stream);

    k_count_deg<<<(E + 255) / 256, 256, 0, stream>>>(dst, E, degI);
    k_dis<<<(N + 255) / 256, 256, 0, stream>>>(degI, N, disv);
    k_count_batch<<<(N + 255) / 256, 256, 0, stream>>>(batch, N, cntI);

    int nb = (N + 1023) / 1024;
    k_scan1<<<nb, 256, 0, stream>>>(degI, N, offs, bsum);
    k_scan2<<<1, 64, 0, stream>>>(bsum, nb);
    k_scan3<<<(N + 255) / 256, 256, 0, stream>>>(offs, bsum, N);
    k_part<<<(E + 255) / 256, 256, 0, stream>>>(src, dst, E, offs, bcur, pairs);

    const float* xin = x;
    for (int l = 0; l < 3; ++l) {
        const float* W = (const float*)d_in[3 + 2 * l];
        const float* b = (const float*)d_in[4 + 2 * l];
        k_gemm<<<1024, 256, 0, stream>>>(xin, W, disv, bufG, N);
        float* xout = (l == 2) ? (float*)d_out : bufX;
        k_agg<<<(NB + 3) / 4, 256, 0, stream>>>(pairs, offs, bufG, disv, b, batch,
                                                xout, gacc, N, E);
        k_pool<<<(GG * 2 * DD + 255) / 256, 256, 0, stream>>>(gacc, gtot, cntI);
        xin = bufX;
    }
    k_copy<<<(GG * 2 * DD + 255) / 256, 256, 0, stream>>>(gtot, (float*)d_out + nd,
                                                          GG * 2 * DD);
}

// Round 4
// 345.722 us; speedup vs baseline: 3.3785x; 1.5486x over previous
//
#include <hip/hip_runtime.h>
#include <hip/hip_fp16.h>

#define DD 64   // feature dim
#define GG 64   // graphs per batch
#define CHUNK 16  // nodes per bucket (one wave per bucket)

typedef _Float16 half8 __attribute__((ext_vector_type(8)));
typedef float floatx4 __attribute__((ext_vector_type(4)));

// ---------------- degree count (in-edges, excl self-loop) ----------------
__global__ __launch_bounds__(256) void k_count_deg(const int* __restrict__ dst, int E,
                                                   int* __restrict__ degI) {
    int i = blockIdx.x * 256 + threadIdx.x;
    if (i < E) atomicAdd(&degI[dst[i]], 1);
}

// dis = rsqrt(deg + 1)  (self-loop included in normalization)
__global__ __launch_bounds__(256) void k_dis(const int* __restrict__ degI, int N,
                                             float* __restrict__ disv) {
    int i = blockIdx.x * 256 + threadIdx.x;
    if (i < N) disv[i] = rsqrtf((float)(degI[i] + 1));
}

// ---------------- nodes-per-graph counts ----------------
__global__ __launch_bounds__(256) void k_count_batch(const int* __restrict__ batch, int N,
                                                     int* __restrict__ cntI) {
    __shared__ int h[GG];
    if (threadIdx.x < GG) h[threadIdx.x] = 0;
    __syncthreads();
    int i = blockIdx.x * 256 + threadIdx.x;
    if (i < N) atomicAdd(&h[batch[i]], 1);
    __syncthreads();
    if (threadIdx.x < GG) {
        int v = h[threadIdx.x];
        if (v) atomicAdd(&cntI[threadIdx.x], v);
    }
}

// ---------------- exclusive scan of degI -> offs (3-pass) ----------------
__global__ __launch_bounds__(256) void k_scan1(const int* __restrict__ degI, int N,
                                               int* __restrict__ offs,
                                               int* __restrict__ bsum) {
    __shared__ int sh[256];
    int t = threadIdx.x;
    int base = blockIdx.x * 1024 + t * 4;
    int v0 = (base + 0 < N) ? degI[base + 0] : 0;
    int v1 = (base + 1 < N) ? degI[base + 1] : 0;
    int v2 = (base + 2 < N) ? degI[base + 2] : 0;
    int v3 = (base + 3 < N) ? degI[base + 3] : 0;
    int s = v0 + v1 + v2 + v3;
    sh[t] = s;
    __syncthreads();
    for (int off = 1; off < 256; off <<= 1) {
        int x = (t >= off) ? sh[t - off] : 0;
        __syncthreads();
        sh[t] += x;
        __syncthreads();
    }
    int excl = sh[t] - s;
    if (t == 255) bsum[blockIdx.x] = sh[255];
    if (base + 0 < N) offs[base + 0] = excl;
    excl += v0;
    if (base + 1 < N) offs[base + 1] = excl;
    excl += v1;
    if (base + 2 < N) offs[base + 2] = excl;
    excl += v2;
    if (base + 3 < N) offs[base + 3] = excl;
}

__global__ void k_scan2(int* __restrict__ bsum, int nb) {
    if (threadIdx.x == 0 && blockIdx.x == 0) {
        int run = 0;
        for (int j = 0; j < nb; ++j) {
            int t = bsum[j];
            bsum[j] = run;
            run += t;
        }
    }
}

__global__ __launch_bounds__(256) void k_scan3(int* __restrict__ offs,
                                               const int* __restrict__ bsum, int N) {
    int i = blockIdx.x * 256 + threadIdx.x;
    if (i < N) offs[i] += bsum[i >> 10];
}

// ---------------- bucketed partition: pairs[boffs[b] + slot] = src | local<<20 ----
__global__ __launch_bounds__(256) void k_part(const int* __restrict__ src,
                                              const int* __restrict__ dst, int E,
                                              const int* __restrict__ offs,
                                              int* __restrict__ bcur,
                                              unsigned* __restrict__ pairs) {
    int i = blockIdx.x * 256 + threadIdx.x;
    if (i < E) {
        int d  = dst[i];
        int bu = d >> 4;
        int p  = atomicAdd(&bcur[bu], 1);
        pairs[offs[bu << 4] + p] = (unsigned)src[i] | ((unsigned)(d & 15) << 20);
    }
}

// ---------------- g = fp16((x @ W) * dis[row])  — MFMA version ----------------
// wave computes a 16-row x 64-col tile: 4 C-frags (16x16), K=64 via 2 steps of 32.
// A: row = lane&15, k = (lane>>4)*8 + e + s*32
// B: col = lane&15, same k mapping
// C/D: col = lane&15, row = (lane>>4)*4 + j
__global__ __launch_bounds__(256) void k_gemm(const float* __restrict__ x,
                                              const float* __restrict__ W,
                                              const float* __restrict__ disv,
                                              __half* __restrict__ g, int N) {
    int lane = threadIdx.x & 63;
    int wave = (blockIdx.x * 256 + threadIdx.x) >> 6;
    int nw   = (gridDim.x * 256) >> 6;
    int col  = lane & 15;
    int krow = (lane >> 4) * 8;

    // W fragments: bf[s][n][e] = W[krow + e + s*32][n*16 + col]  (once per wave)
    half8 bf[2][4];
#pragma unroll
    for (int s = 0; s < 2; ++s)
#pragma unroll
        for (int n = 0; n < 4; ++n)
#pragma unroll
            for (int e = 0; e < 8; ++e)
                bf[s][n][e] = (_Float16)W[(size_t)(krow + e + s * 32) * DD + n * 16 + col];

    int nch = (N + 15) >> 4;
    for (int c = wave; c < nch; c += nw) {
        int base = c * 16;
        int arow = base + (lane & 15);
        const float* xr = x + (size_t)min(arow, N - 1) * DD + krow;
        half8 af[2];
#pragma unroll
        for (int s = 0; s < 2; ++s) {
            float4 lo = *(const float4*)(xr + s * 32);
            float4 hi = *(const float4*)(xr + s * 32 + 4);
            af[s][0] = (_Float16)lo.x; af[s][1] = (_Float16)lo.y;
            af[s][2] = (_Float16)lo.z; af[s][3] = (_Float16)lo.w;
            af[s][4] = (_Float16)hi.x; af[s][5] = (_Float16)hi.y;
            af[s][6] = (_Float16)hi.z; af[s][7] = (_Float16)hi.w;
        }
        floatx4 acc[4] = {{0.f, 0.f, 0.f, 0.f}, {0.f, 0.f, 0.f, 0.f},
                          {0.f, 0.f, 0.f, 0.f}, {0.f, 0.f, 0.f, 0.f}};
#pragma unroll
        for (int s = 0; s < 2; ++s)
#pragma unroll
            for (int n = 0; n < 4; ++n)
                acc[n] = __builtin_amdgcn_mfma_f32_16x16x32_f16(af[s], bf[s][n],
                                                                acc[n], 0, 0, 0);
#pragma unroll
        for (int j = 0; j < 4; ++j) {
            int rr = base + (lane >> 4) * 4 + j;
            if (rr < N) {
                float dv = disv[rr];
#pragma unroll
                for (int n = 0; n < 4; ++n)
                    g[(size_t)rr * DD + n * 16 + col] = __float2half(acc[n][j] * dv);
            }
        }
    }
}

// ---------------- fused aggregate + finalize + pooling (one wave per bucket) ----
__global__ __launch_bounds__(256) void k_agg(const unsigned* __restrict__ pairs,
                                             const int* __restrict__ offs,
                                             const __half* __restrict__ g,
                                             const float* __restrict__ disv,
                                             const float* __restrict__ b,
                                             const int* __restrict__ batch,
                                             float* __restrict__ xout,
                                             float* __restrict__ gacc, int N, int E) {
    __shared__ float acc_s[4][CHUNK * DD];   // 16 KB/block, wave-private slices
    int lane = threadIdx.x & 63;
    int w    = threadIdx.x >> 6;
    float* acc = acc_s[w];
    int wave = (blockIdx.x * 256 + threadIdx.x) >> 6;
    int nw   = (gridDim.x * 256) >> 6;
    int NB   = (N + CHUNK - 1) / CHUNK;
    float bj = b[lane];
    for (int bu = wave; bu < NB; bu += nw) {
        int nbase  = bu * CHUNK;
        int nend   = min(nbase + CHUNK, N);
        int bstart = offs[nbase];
        int bend   = (nbase + CHUNK >= N) ? E : offs[nbase + CHUNK];
#pragma unroll
        for (int t = 0; t < CHUNK; ++t) acc[t * DD + lane] = 0.f;
        for (int k = bstart; k < bend; k += 64) {
            int kk = min(bend - k, 64);
            unsigned pk = (lane < kk) ? pairs[k + lane] : 0u;
            int j = 0;
            for (; j + 3 < kk; j += 4) {
                unsigned p0 = __shfl(pk, j + 0);
                unsigned p1 = __shfl(pk, j + 1);
                unsigned p2 = __shfl(pk, j + 2);
                unsigned p3 = __shfl(pk, j + 3);
                float v0 = __half2float(g[(size_t)(p0 & 0xFFFFFu) * DD + lane]);
                float v1 = __half2float(g[(size_t)(p1 & 0xFFFFFu) * DD + lane]);
                float v2 = __half2float(g[(size_t)(p2 & 0xFFFFFu) * DD + lane]);
                float v3 = __half2float(g[(size_t)(p3 & 0xFFFFFu) * DD + lane]);
                acc[(p0 >> 20) * DD + lane] += v0;
                acc[(p1 >> 20) * DD + lane] += v1;
                acc[(p2 >> 20) * DD + lane] += v2;
                acc[(p3 >> 20) * DD + lane] += v3;
            }
            for (; j < kk; ++j) {
                unsigned p = __shfl(pk, j);
                acc[(p >> 20) * DD + lane] +=
                    __half2float(g[(size_t)(p & 0xFFFFFu) * DD + lane]);
            }
        }
        // finalize 16 nodes + fused pooling (batch is sorted)
        float vmax = 0.f, vsum = 0.f;
        int curg = batch[nbase];
        for (int i = nbase; i < nend; ++i) {
            float self = __half2float(g[(size_t)i * DD + lane]);
            float v = disv[i] * (acc[(i - nbase) * DD + lane] + self) + bj;
            v = fmaxf(v, 0.f);
            xout[(size_t)i * DD + lane] = v;
            int gid = batch[i];
            if (gid != curg) {
                atomicMax((unsigned*)&gacc[curg * 2 * DD + lane], __float_as_uint(vmax));
                atomicAdd(&gacc[curg * 2 * DD + DD + lane], vsum);
                vmax = 0.f; vsum = 0.f; curg = gid;
            }
            vmax = fmaxf(vmax, v);
            vsum += v;
        }
        atomicMax((unsigned*)&gacc[curg * 2 * DD + lane], __float_as_uint(vmax));
        atomicAdd(&gacc[curg * 2 * DD + DD + lane], vsum);
    }
}

// ---------------- fold per-layer pool into running total; clear gacc ----------------
__global__ __launch_bounds__(256) void k_pool(float* __restrict__ gacc,
                                              float* __restrict__ gtot,
                                              const int* __restrict__ cntI) {
    int i = blockIdx.x * 256 + threadIdx.x;
    if (i < GG * 2 * DD) {
        int gidx = i >> 7;
        int j    = i & 127;
        float v  = gacc[i];
        if (j >= DD) v = v / (float)cntI[gidx];
        gtot[i] += v;
        gacc[i] = 0.f;
    }
}

__global__ __launch_bounds__(256) void k_copy(const float* __restrict__ srcp,
                                              float* __restrict__ dstp, int n) {
    int i = blockIdx.x * 256 + threadIdx.x;
    if (i < n) dstp[i] = srcp[i];
}

extern "C" void kernel_launch(void* const* d_in, const int* in_sizes, int n_in,
                              void* d_out, int out_size, void* d_ws, size_t ws_size,
                              hipStream_t stream) {
    const float* x     = (const float*)d_in[0];
    const int*   ei    = (const int*)d_in[1];
    const int*   batch = (const int*)d_in[2];

    int N = in_sizes[0] / DD;
    int E = in_sizes[1] / 2;
    const int* src = ei;
    const int* dst = ei + E;

    size_t nd = (size_t)N * DD;
    int NB = (N + CHUNK - 1) / CHUNK;

    float*    ws    = (float*)d_ws;
    float*    bufX  = ws;                       // N*DD f32 intermediate features
    __half*   bufG  = (__half*)(ws + nd);       // N*DD fp16 messages (g)
    float*    disv  = ws + nd + nd / 2;         // N f32
    float*    gacc  = disv + N;                 // GG*2*DD
    float*    gtot  = gacc + GG * 2 * DD;       // GG*2*DD
    int*      cntI  = (int*)(gtot + GG * 2 * DD);  // GG
    int*      degI  = cntI + GG;                // N
    int*      offs  = degI + N;                 // N
    int*      bcur  = offs + N;                 // NB
    int*      bsum  = bcur + NB;                // 128
    unsigned* pairs = (unsigned*)(bsum + 128);  // E

    hipMemsetAsync(degI, 0, (size_t)N * sizeof(int), stream);
    hipMemsetAsync(bcur, 0, (size_t)NB * sizeof(int), stream);
    hipMemsetAsync(gacc, 0, (size_t)GG * 2 * DD * sizeof(float), stream);
    hipMemsetAsync(gtot, 0, (size_t)GG * 2 * DD * sizeof(float), stream);
    hipMemsetAsync(cntI, 0, (size_t)GG * sizeof(int), stream);

    k_count_deg<<<(E + 255) / 256, 256, 0, stream>>>(dst, E, degI);
    k_dis<<<(N + 255) / 256, 256, 0, stream>>>(degI, N, disv);
    k_count_batch<<<(N + 255) / 256, 256, 0, stream>>>(batch, N, cntI);

    int nb = (N + 1023) / 1024;
    k_scan1<<<nb, 256, 0, stream>>>(degI, N, offs, bsum);
    k_scan2<<<1, 64, 0, stream>>>(bsum, nb);
    k_scan3<<<(N + 255) / 256, 256, 0, stream>>>(offs, bsum, N);
    k_part<<<(E + 255) / 256, 256, 0, stream>>>(src, dst, E, offs, bcur, pairs);

    const float* xin = x;
    for (int l = 0; l < 3; ++l) {
        const float* W = (const float*)d_in[3 + 2 * l];
        const float* b = (const float*)d_in[4 + 2 * l];
        k_gemm<<<400, 256, 0, stream>>>(xin, W, disv, bufG, N);
        float* xout = (l == 2) ? (float*)d_out : bufX;
        k_agg<<<(NB + 3) / 4, 256, 0, stream>>>(pairs, offs, bufG, disv, b, batch,
                                                xout, gacc, N, E);
        k_pool<<<(GG * 2 * DD + 255) / 256, 256, 0, stream>>>(gacc, gtot, cntI);
        xin = bufX;
    }
    k_copy<<<(GG * 2 * DD + 255) / 256, 256, 0, stream>>>(gtot, (float*)d_out + nd,
                                                          GG * 2 * DD);
}